// Round 2
// baseline (1463.497 us; speedup 1.0000x reference)
//
#include <hip/hip_runtime.h>

#define EPS 1e-5f

__device__ __forceinline__ float fexp(float x){ return __builtin_amdgcn_exp2f(x*1.4426950408889634f); }
__device__ __forceinline__ float frcp(float x){ return __builtin_amdgcn_rcpf(x); }
__device__ __forceinline__ float fsig(float x){ return frcp(1.0f + fexp(-x)); }
__device__ __forceinline__ float ftanh(float x){ return 1.0f - 2.0f*frcp(fexp(2.0f*x) + 1.0f); }

// ---------------- mean(x) reduction (deterministic, 2-stage) ----------------
__global__ void mean_part(const float* __restrict__ x, int P, float* __restrict__ part)
{
    __shared__ float red[256];
    int tid = blockIdx.x*256 + threadIdx.x;
    float s = 0.0f;
    for (int i = tid; i < P; i += 256*1024) s += x[i];
    red[threadIdx.x] = s; __syncthreads();
    for (int w = 128; w > 0; w >>= 1){
        if (threadIdx.x < w) red[threadIdx.x] += red[threadIdx.x + w];
        __syncthreads();
    }
    if (threadIdx.x == 0) part[blockIdx.x] = red[0];
}

__global__ void mean_fin(const float* __restrict__ part, float* __restrict__ ws, int P)
{
    __shared__ float red[1024];
    int t = threadIdx.x;
    red[t] = part[t]; __syncthreads();
    for (int w = 512; w > 0; w >>= 1){
        if (t < w) red[t] += red[t + w];
        __syncthreads();
    }
    if (t == 0) ws[0] = red[0] / (float)P;
}

// ---------------- per-layer constant: add = LN(bh,gh,bgh) + bgi ----------------
// (hx=0 so the hidden-path LN is a constant vector; f-gate handled directly now)
// ws layout (floats): [0]=mean_x, [16..1040)=partials, [1056..1312)=add0, [1312..1568)=add1
__global__ void precomp_kernel(
    const float* __restrict__ bh0, const float* __restrict__ gh0,
    const float* __restrict__ bgh0, const float* __restrict__ bgi0,
    const float* __restrict__ bh1, const float* __restrict__ gh1,
    const float* __restrict__ bgh1, const float* __restrict__ bgi1,
    float* __restrict__ ws)
{
    const int l = blockIdx.x;
    const float* bh  = l ? bh1  : bh0;
    const float* gh  = l ? gh1  : gh0;
    const float* bgh = l ? bgh1 : bgh0;
    const float* bgi = l ? bgi1 : bgi0;
    float* add = ws + 1056 + l*256;
    int t = threadIdx.x;

    __shared__ float r1[256], r2[256];
    float v = bh[t];
    r1[t] = v; r2[t] = v*v; __syncthreads();
    for (int w = 128; w > 0; w >>= 1){
        if (t < w){ r1[t] += r1[t+w]; r2[t] += r2[t+w]; }
        __syncthreads();
    }
    float m   = r1[0] * (1.0f/256.0f);
    float var = (r2[0] - 256.0f*m*m) * (1.0f/255.0f);
    float s   = sqrtf(fmaxf(var, 0.0f));
    float c   = (v - m) * frcp(s + EPS) * gh[t] + bgh[t];
    add[t] = c + bgi[t];
}

// ---------------- weight staging: rows skewed by 4 floats every 16 rows ----------------
// LDS float-offset of W[r][k] = r*64 + (r>>4)*4 + k   (16B-aligned rows; sub-lane
// reads hit disjoint bank quads for every exchange round)
__device__ __forceinline__ void stage_w(const float* __restrict__ W, float* __restrict__ wlds, int tid)
{
    #pragma unroll
    for (int i = 0; i < 8; ++i){
        int idx = tid + i*512;            // 0..4095 float4 chunks
        int r   = idx >> 4;
        int c4  = (idx & 15) << 2;
        const float4 v = *(const float4*)(W + r*64 + c4);
        *(float4*)(wlds + r*64 + ((r>>4)<<2) + c4) = v;
    }
}

// ---------------- fused LSTM-cell layer (hx = cx = 0), 4 lanes per row ----------------
// lane sub-id s owns cells c0..c0+15 (c0 = s*16); h[16] is this lane's chunk.
__device__ __forceinline__ void lstm_layer(float (&h)[16], const float* __restrict__ wlds, int s,
    const float* __restrict__ bi, const float* __restrict__ gi,
    const float* __restrict__ add, const float* __restrict__ gc, const float* __restrict__ bc)
{
    const int c0 = s << 4;
    float za[4][16];                      // gates i,f,o,g for owned cells
    #pragma unroll
    for (int t = 0; t < 16; ++t){
        za[0][t] = bi[      c0+t];
        za[1][t] = bi[ 64 + c0+t];
        za[2][t] = bi[128 + c0+t];
        za[3][t] = bi[192 + c0+t];
    }

    #pragma unroll 1
    for (int j = 0; j < 4; ++j){          // h-chunk exchange rounds
        const int sj16 = ((s ^ j) << 4);
        float hs[16];
        #pragma unroll
        for (int k = 0; k < 16; ++k) hs[k] = __shfl_xor(h[k], j);
        #pragma unroll
        for (int t = 0; t < 16; ++t){
            const int r0 = (      c0+t) << 6;
            const int r1 = ( 64 + c0+t) << 6;
            const int r2 = (128 + c0+t) << 6;
            const int r3 = (192 + c0+t) << 6;
            #pragma unroll
            for (int kc = 0; kc < 4; ++kc){
                const int ko = sj16 + (kc << 2);
                const float4 w0 = *(const float4*)(wlds + r0 + ((     s) << 2) + ko);
                const float4 w1 = *(const float4*)(wlds + r1 + (( 4 + s) << 2) + ko);
                const float4 w2 = *(const float4*)(wlds + r2 + (( 8 + s) << 2) + ko);
                const float4 w3 = *(const float4*)(wlds + r3 + ((12 + s) << 2) + ko);
                const float h0 = hs[kc*4+0], h1 = hs[kc*4+1], h2 = hs[kc*4+2], h3 = hs[kc*4+3];
                za[0][t] += h0*w0.x; za[1][t] += h0*w1.x; za[2][t] += h0*w2.x; za[3][t] += h0*w3.x;
                za[0][t] += h1*w0.y; za[1][t] += h1*w1.y; za[2][t] += h1*w2.y; za[3][t] += h1*w3.y;
                za[0][t] += h2*w0.z; za[1][t] += h2*w1.z; za[2][t] += h2*w2.z; za[3][t] += h2*w3.z;
                za[0][t] += h3*w0.w; za[1][t] += h3*w1.w; za[2][t] += h3*w2.w; za[3][t] += h3*w3.w;
            }
        }
    }

    // LN stats over all 256 z of this row (4-lane butterfly)
    float sm = 0.f, sq = 0.f;
    #pragma unroll
    for (int t = 0; t < 16; ++t){
        sm += za[0][t] + za[1][t] + za[2][t] + za[3][t];
        sq += za[0][t]*za[0][t] + za[1][t]*za[1][t] + za[2][t]*za[2][t] + za[3][t]*za[3][t];
    }
    sm += __shfl_xor(sm, 1); sm += __shfl_xor(sm, 2);
    sq += __shfl_xor(sq, 1); sq += __shfl_xor(sq, 2);
    const float m   = sm * (1.0f/256.0f);
    const float var = (sq - 256.0f*m*m) * (1.0f/255.0f);
    const float inv = frcp(sqrtf(fmaxf(var, 0.0f)) + EPS);

    // gates (f only contributed to stats; cx_prev = 0)
    #pragma unroll
    for (int t = 0; t < 16; ++t){
        const int c = c0 + t;
        const float i_ = (za[0][t]-m)*inv*gi[      c] + add[      c];
        const float o_ = (za[2][t]-m)*inv*gi[128 + c] + add[128 + c];
        const float g_ = (za[3][t]-m)*inv*gi[192 + c] + add[192 + c];
        za[0][t] = fsig(i_) * ftanh(g_);   // cx
        za[2][t] = o_;                      // oo
    }

    // hx = sigmoid(o) * tanh(LN(cx, gc, bc))  (64-wide LN, 4-lane butterfly)
    float s2 = 0.f, q2 = 0.f;
    #pragma unroll
    for (int t = 0; t < 16; ++t){ s2 += za[0][t]; q2 += za[0][t]*za[0][t]; }
    s2 += __shfl_xor(s2, 1); s2 += __shfl_xor(s2, 2);
    q2 += __shfl_xor(q2, 1); q2 += __shfl_xor(q2, 2);
    const float mc = s2 * (1.0f/64.0f);
    const float vc = (q2 - 64.0f*mc*mc) * (1.0f/63.0f);
    const float ic = frcp(sqrtf(fmaxf(vc, 0.0f)) + EPS);
    #pragma unroll
    for (int t = 0; t < 16; ++t){
        const int c = c0 + t;
        h[t] = fsig(za[2][t]) * ftanh((za[0][t]-mc)*ic*gc[c] + bc[c]);
    }
}

// ---------------- main: 4 lanes per row, 128 rows per 512-thread block ----------------
__global__ __launch_bounds__(512, 2) void fwd_kernel(
    const float* __restrict__ x,
    const float* __restrict__ W1, const float* __restrict__ b1,
    const float* __restrict__ g1, const float* __restrict__ be1,
    const float* __restrict__ Wi0, const float* __restrict__ bi0,
    const float* __restrict__ gi0, const float* __restrict__ gc0, const float* __restrict__ bc0,
    const float* __restrict__ Wi1, const float* __restrict__ bi1,
    const float* __restrict__ gi1, const float* __restrict__ gc1, const float* __restrict__ bc1,
    const float* __restrict__ Wo, const float* __restrict__ bo,
    const float* __restrict__ ws, float* __restrict__ out, int P)
{
    __shared__ float wlds[16448];
    const int tid = threadIdx.x;
    const int s   = tid & 3;
    const int row = blockIdx.x*128 + (tid >> 2);
    const int c0  = s << 4;

    stage_w(Wi0, wlds, tid);

    float xv = 0.f;
    if (row < P) xv = x[row];
    else if (row == P) xv = ws[0];

    // h = tanh(LN(x*W1 + b1, g1, be1)) — 64-wide LN across the 4-lane group
    float h[16];
    float sm = 0.f, sq = 0.f;
    #pragma unroll
    for (int t = 0; t < 16; ++t){
        float v = xv*W1[c0+t] + b1[c0+t];
        h[t] = v; sm += v; sq += v*v;
    }
    sm += __shfl_xor(sm, 1); sm += __shfl_xor(sm, 2);
    sq += __shfl_xor(sq, 1); sq += __shfl_xor(sq, 2);
    const float m   = sm * (1.0f/64.0f);
    const float var = (sq - 64.0f*m*m) * (1.0f/63.0f);
    const float inv = frcp(sqrtf(fmaxf(var, 0.0f)) + EPS);
    #pragma unroll
    for (int t = 0; t < 16; ++t)
        h[t] = ftanh((h[t]-m)*inv*g1[c0+t] + be1[c0+t]);

    __syncthreads();                       // staging of Wi0 complete
    lstm_layer(h, wlds, s, bi0, gi0, ws + 1056, gc0, bc0);

    __syncthreads();                       // everyone done with Wi0
    stage_w(Wi1, wlds, tid);
    __syncthreads();                       // staging of Wi1 complete
    lstm_layer(h, wlds, s, bi1, gi1, ws + 1312, gc1, bc1);

    float o = 0.f;
    #pragma unroll
    for (int t = 0; t < 16; ++t) o += h[t]*Wo[c0+t];
    o += __shfl_xor(o, 1); o += __shfl_xor(o, 2);
    if (s == 0 && row <= P) out[row] = o + bo[0];
}

extern "C" void kernel_launch(void* const* d_in, const int* in_sizes, int n_in,
                              void* d_out, int out_size, void* d_ws, size_t ws_size,
                              hipStream_t stream)
{
    (void)n_in; (void)out_size; (void)ws_size;
    const float* x     = (const float*)d_in[0];
    const float* W1    = (const float*)d_in[1];
    const float* b1    = (const float*)d_in[2];
    const float* g1    = (const float*)d_in[3];
    const float* be1   = (const float*)d_in[4];
    const float* l0_Wi = (const float*)d_in[5];
    const float* l0_bi = (const float*)d_in[6];
    const float* l0_bh = (const float*)d_in[8];
    const float* l0_gi = (const float*)d_in[9];
    const float* l0_bgi= (const float*)d_in[10];
    const float* l0_gh = (const float*)d_in[11];
    const float* l0_bgh= (const float*)d_in[12];
    const float* l0_gc = (const float*)d_in[13];
    const float* l0_bc = (const float*)d_in[14];
    const float* l1_Wi = (const float*)d_in[15];
    const float* l1_bi = (const float*)d_in[16];
    const float* l1_bh = (const float*)d_in[18];
    const float* l1_gi = (const float*)d_in[19];
    const float* l1_bgi= (const float*)d_in[20];
    const float* l1_gh = (const float*)d_in[21];
    const float* l1_bgh= (const float*)d_in[22];
    const float* l1_gc = (const float*)d_in[23];
    const float* l1_bc = (const float*)d_in[24];
    const float* Wo    = (const float*)d_in[25];
    const float* bo    = (const float*)d_in[26];

    int P = in_sizes[0];
    int B = P + 1;                 // rows
    float* ws  = (float*)d_ws;
    float* out = (float*)d_out;

    mean_part<<<1024, 256, 0, stream>>>(x, P, ws + 16);
    mean_fin<<<1, 1024, 0, stream>>>(ws + 16, ws, P);
    precomp_kernel<<<2, 256, 0, stream>>>(
        l0_bh, l0_gh, l0_bgh, l0_bgi,
        l1_bh, l1_gh, l1_bgh, l1_bgi, ws);
    fwd_kernel<<<(B + 127)/128, 512, 0, stream>>>(
        x, W1, b1, g1, be1,
        l0_Wi, l0_bi, l0_gi, l0_gc, l0_bc,
        l1_Wi, l1_bi, l1_gi, l1_gc, l1_bc,
        Wo, bo, ws, out, P);
}

// Round 3
// 228.410 us; speedup vs baseline: 6.4073x; 6.4073x over previous
//
#include <hip/hip_runtime.h>

#define EPS 1e-5f

typedef __attribute__((ext_vector_type(8))) short bf16x8;
typedef __attribute__((ext_vector_type(4))) short short4v;
typedef __attribute__((ext_vector_type(4))) float f32x4;

__device__ __forceinline__ float fexp(float x){ return __builtin_amdgcn_exp2f(x*1.4426950408889634f); }
__device__ __forceinline__ float frcp(float x){ return __builtin_amdgcn_rcpf(x); }
__device__ __forceinline__ float fsig(float x){ return frcp(1.0f + fexp(-x)); }
__device__ __forceinline__ float ftanh(float x){ return 1.0f - 2.0f*frcp(fexp(2.0f*x) + 1.0f); }

__device__ __forceinline__ short bfhi(float v){ return (short)(__float_as_uint(v) >> 16); }
__device__ __forceinline__ float bfhif(float v){ return __uint_as_float(__float_as_uint(v) & 0xFFFF0000u); }

// ---------------- mean(x) reduction (deterministic, 2-stage) ----------------
__global__ void mean_part(const float* __restrict__ x, int P, float* __restrict__ part)
{
    __shared__ float red[256];
    int tid = blockIdx.x*256 + threadIdx.x;
    float s = 0.0f;
    for (int i = tid; i < P; i += 256*1024) s += x[i];
    red[threadIdx.x] = s; __syncthreads();
    for (int w = 128; w > 0; w >>= 1){
        if (threadIdx.x < w) red[threadIdx.x] += red[threadIdx.x + w];
        __syncthreads();
    }
    if (threadIdx.x == 0) part[blockIdx.x] = red[0];
}

__global__ void mean_fin(const float* __restrict__ part, float* __restrict__ ws, int P)
{
    __shared__ float red[1024];
    int t = threadIdx.x;
    red[t] = part[t]; __syncthreads();
    for (int w = 512; w > 0; w >>= 1){
        if (t < w) red[t] += red[t + w];
        __syncthreads();
    }
    if (t == 0) ws[0] = red[0] / (float)P;
}

// ---------------- per-layer constant: add = LN(bh,gh,bgh) + bgi ----------------
// ws layout (floats): [0]=mean_x, [16..1040)=partials, [1056..1312)=add0, [1312..1568)=add1
__global__ void precomp_kernel(
    const float* __restrict__ bh0, const float* __restrict__ gh0,
    const float* __restrict__ bgh0, const float* __restrict__ bgi0,
    const float* __restrict__ bh1, const float* __restrict__ gh1,
    const float* __restrict__ bgh1, const float* __restrict__ bgi1,
    float* __restrict__ ws)
{
    const int l = blockIdx.x;
    const float* bh  = l ? bh1  : bh0;
    const float* gh  = l ? gh1  : gh0;
    const float* bgh = l ? bgh1 : bgh0;
    const float* bgi = l ? bgi1 : bgi0;
    float* add = ws + 1056 + l*256;
    int t = threadIdx.x;

    __shared__ float r1[256], r2[256];
    float v = bh[t];
    r1[t] = v; r2[t] = v*v; __syncthreads();
    for (int w = 128; w > 0; w >>= 1){
        if (t < w){ r1[t] += r1[t+w]; r2[t] += r2[t+w]; }
        __syncthreads();
    }
    float m   = r1[0] * (1.0f/256.0f);
    float var = (r2[0] - 256.0f*m*m) * (1.0f/255.0f);
    float s   = sqrtf(fmaxf(var, 0.0f));
    float c   = (v - m) * frcp(s + EPS) * gh[t] + bgh[t];
    add[t] = c + bgi[t];
}

// ---------------- main fused kernel ----------------
// Block: 512 threads = 8 waves; wave handles 16 rows (batch), block handles 128.
// GEMM orientation (swapped): M = 256 gates, N = 16 rows, K = 64.
// D-layout (m89): m(tile) = (lane>>4)*4 + reg, n = lane&15.
// LDS: wl = W split hi/lo, swizzled; restaged per layer. hb = per-wave h (split).
__global__ __launch_bounds__(512, 2) void fwd_kernel(
    const float* __restrict__ x,
    const float* __restrict__ W1, const float* __restrict__ b1,
    const float* __restrict__ g1, const float* __restrict__ be1,
    const float* __restrict__ Wi0, const float* __restrict__ bi0,
    const float* __restrict__ gi0, const float* __restrict__ gc0, const float* __restrict__ bc0,
    const float* __restrict__ Wi1, const float* __restrict__ bi1,
    const float* __restrict__ gi1, const float* __restrict__ gc1, const float* __restrict__ bc1,
    const float* __restrict__ Wo, const float* __restrict__ bo,
    const float* __restrict__ ws, float* __restrict__ out, int P)
{
    __shared__ short wl[32768];   // [part(2)][g(256)][k(64)] swizzled  (64 KB)
    __shared__ short hb[16384];   // [wave(8)][part(2)][row(16)][cell(64)] swizzled (32 KB)

    const int tid  = threadIdx.x;
    const int wid  = tid >> 6;
    const int lane = tid & 63;
    const int c16  = lane & 15;          // batch-row within wave / n-index
    const int q    = lane >> 4;          // 0..3
    const int row  = blockIdx.x*128 + wid*16 + c16;
    short* hbw = hb + wid*2048;
    const int swz = (c16 & 7) << 3;      // hb swizzle for this lane's row

    // ---- stage W (fp32 -> bf16 hi/lo, swizzled) ----
    auto stage = [&](const float* __restrict__ W){
        #pragma unroll
        for (int i = 0; i < 8; ++i){
            int idx = i*512 + tid;                  // float4 chunk 0..4095
            int g = idx >> 4, k0 = (idx & 15) << 2;
            f32x4 w4 = *(const f32x4*)(W + (idx << 2));
            int si = ((g << 6) + k0) ^ ((g & 7) << 3);
            short4v hi = { bfhi(w4[0]), bfhi(w4[1]), bfhi(w4[2]), bfhi(w4[3]) };
            short4v lo = { bfhi(w4[0]-bfhif(w4[0])), bfhi(w4[1]-bfhif(w4[1])),
                           bfhi(w4[2]-bfhif(w4[2])), bfhi(w4[3]-bfhif(w4[3])) };
            *(short4v*)(wl + si)         = hi;
            *(short4v*)(wl + 16384 + si) = lo;
        }
    };

    stage(Wi0);

    // ---- input layer: h = tanh(LN64(x*W1 + b1)) ; lane owns cells q*16..+15 ----
    float xv = 0.0f;
    if (row < P) xv = x[row];
    else if (row == P) xv = ws[0];

    {
        const int cb = q << 4;
        float h[16]; float sm = 0.f, sq = 0.f;
        #pragma unroll
        for (int j = 0; j < 16; ++j){
            float v = xv*W1[cb+j] + b1[cb+j];
            h[j] = v; sm += v; sq += v*v;
        }
        sm += __shfl_xor(sm, 16); sm += __shfl_xor(sm, 32);
        sq += __shfl_xor(sq, 16); sq += __shfl_xor(sq, 32);
        const float m   = sm * (1.0f/64.0f);
        const float var = (sq - 64.0f*m*m) * (1.0f/63.0f);
        const float inv = frcp(sqrtf(fmaxf(var, 0.0f)) + EPS);
        #pragma unroll
        for (int j = 0; j < 16; ++j)
            h[j] = ftanh((h[j]-m)*inv*g1[cb+j] + be1[cb+j]);
        #pragma unroll
        for (int j4 = 0; j4 < 4; ++j4){
            int si = ((c16 << 6) + cb + (j4 << 2)) ^ swz;
            short4v hi = { bfhi(h[j4*4+0]), bfhi(h[j4*4+1]), bfhi(h[j4*4+2]), bfhi(h[j4*4+3]) };
            short4v lo = { bfhi(h[j4*4+0]-bfhif(h[j4*4+0])), bfhi(h[j4*4+1]-bfhif(h[j4*4+1])),
                           bfhi(h[j4*4+2]-bfhif(h[j4*4+2])), bfhi(h[j4*4+3]-bfhif(h[j4*4+3])) };
            *(short4v*)(hbw + si)        = hi;
            *(short4v*)(hbw + 1024 + si) = lo;
        }
    }
    __syncthreads();   // wl(L0) staged + hb(input) written

    float hout[16];

    auto do_layer = [&](const float* __restrict__ bi, const float* __restrict__ gi,
                        const float* __restrict__ addv, const float* __restrict__ gc,
                        const float* __restrict__ bc, bool writeback){
        // B-frags (h of this wave's rows), resident
        bf16x8 bhh[2], bhl[2];
        #pragma unroll
        for (int ks = 0; ks < 2; ++ks){
            int si = ((c16 << 6) + ks*32 + (q << 3)) ^ swz;
            bhh[ks] = *(const bf16x8*)(hbw + si);
            bhl[ks] = *(const bf16x8*)(hbw + 1024 + si);
        }
        // acc init = bi (z bias), D-layout: gate g = mt*16 + q*4 + reg
        f32x4 acc[16];
        #pragma unroll
        for (int mt = 0; mt < 16; ++mt)
            acc[mt] = *(const f32x4*)(bi + mt*16 + (q << 2));
        // GEMM: z += W * h   (3-term bf16 split)
        #pragma unroll
        for (int mt = 0; mt < 16; ++mt){
            #pragma unroll
            for (int ks = 0; ks < 2; ++ks){
                int si = ((((mt << 4) + c16) << 6) + ks*32 + (q << 3)) ^ swz;  // (g&7)==(c16&7)
                bf16x8 whi = *(const bf16x8*)(wl + si);
                bf16x8 wlo = *(const bf16x8*)(wl + 16384 + si);
                acc[mt] = __builtin_amdgcn_mfma_f32_16x16x32_bf16(whi, bhh[ks], acc[mt], 0, 0, 0);
                acc[mt] = __builtin_amdgcn_mfma_f32_16x16x32_bf16(whi, bhl[ks], acc[mt], 0, 0, 0);
                acc[mt] = __builtin_amdgcn_mfma_f32_16x16x32_bf16(wlo, bhh[ks], acc[mt], 0, 0, 0);
            }
        }
        // LN256 stats (rows = n = c16; partners differ in lane bits 4,5)
        float sm = 0.f, sq = 0.f;
        #pragma unroll
        for (int mt = 0; mt < 16; ++mt){
            #pragma unroll
            for (int r = 0; r < 4; ++r){ float v = acc[mt][r]; sm += v; sq += v*v; }
        }
        sm += __shfl_xor(sm, 16); sm += __shfl_xor(sm, 32);
        sq += __shfl_xor(sq, 16); sq += __shfl_xor(sq, 32);
        const float m   = sm * (1.0f/256.0f);
        const float var = (sq - 256.0f*m*m) * (1.0f/255.0f);
        const float inv = frcp(sqrtf(fmaxf(var, 0.0f)) + EPS);

        // gates: i = mt 0..3, f = 4..7 (stats only), o = 8..11, g = 12..15
        float cx[16], oo[16];
        #pragma unroll
        for (int mt4 = 0; mt4 < 4; ++mt4){
            const f32x4 giI = *(const f32x4*)(gi   +       mt4*16 + (q << 2));
            const f32x4 giO = *(const f32x4*)(gi   + 128 + mt4*16 + (q << 2));
            const f32x4 giG = *(const f32x4*)(gi   + 192 + mt4*16 + (q << 2));
            const f32x4 adI = *(const f32x4*)(addv +       mt4*16 + (q << 2));
            const f32x4 adO = *(const f32x4*)(addv + 128 + mt4*16 + (q << 2));
            const f32x4 adG = *(const f32x4*)(addv + 192 + mt4*16 + (q << 2));
            #pragma unroll
            for (int r = 0; r < 4; ++r){
                const float i_ = (acc[mt4   ][r]-m)*inv*giI[r] + adI[r];
                const float o_ = (acc[mt4+ 8][r]-m)*inv*giO[r] + adO[r];
                const float g_ = (acc[mt4+12][r]-m)*inv*giG[r] + adG[r];
                cx[mt4*4+r] = fsig(i_) * ftanh(g_);
                oo[mt4*4+r] = o_;
            }
        }
        // LN64 over cx, then h' = sig(o)*tanh(LN(cx))
        float s2 = 0.f, q2 = 0.f;
        #pragma unroll
        for (int t = 0; t < 16; ++t){ s2 += cx[t]; q2 += cx[t]*cx[t]; }
        s2 += __shfl_xor(s2, 16); s2 += __shfl_xor(s2, 32);
        q2 += __shfl_xor(q2, 16); q2 += __shfl_xor(q2, 32);
        const float mc = s2 * (1.0f/64.0f);
        const float vc = (q2 - 64.0f*mc*mc) * (1.0f/63.0f);
        const float ic = frcp(sqrtf(fmaxf(vc, 0.0f)) + EPS);
        #pragma unroll
        for (int mt4 = 0; mt4 < 4; ++mt4){
            const f32x4 gc4 = *(const f32x4*)(gc + mt4*16 + (q << 2));
            const f32x4 bc4 = *(const f32x4*)(bc + mt4*16 + (q << 2));
            #pragma unroll
            for (int r = 0; r < 4; ++r)
                hout[mt4*4+r] = fsig(oo[mt4*4+r]) * ftanh((cx[mt4*4+r]-mc)*ic*gc4[r] + bc4[r]);
        }
        if (writeback){
            #pragma unroll
            for (int mt4 = 0; mt4 < 4; ++mt4){
                int si = ((c16 << 6) + mt4*16 + (q << 2)) ^ swz;
                float a = hout[mt4*4+0], b = hout[mt4*4+1], c = hout[mt4*4+2], d = hout[mt4*4+3];
                short4v hi = { bfhi(a), bfhi(b), bfhi(c), bfhi(d) };
                short4v lo = { bfhi(a-bfhif(a)), bfhi(b-bfhif(b)), bfhi(c-bfhif(c)), bfhi(d-bfhif(d)) };
                *(short4v*)(hbw + si)        = hi;
                *(short4v*)(hbw + 1024 + si) = lo;
            }
        }
    };

    do_layer(bi0, gi0, ws + 1056, gc0, bc0, true);
    __syncthreads();   // all waves done reading wl(L0)
    stage(Wi1);
    __syncthreads();   // wl(L1) staged; hb(h1) writes drained
    do_layer(bi1, gi1, ws + 1312, gc1, bc1, false);

    // output: out = h2 . Wo + bo
    float o = 0.f;
    #pragma unroll
    for (int mt4 = 0; mt4 < 4; ++mt4){
        const f32x4 wo4 = *(const f32x4*)(Wo + mt4*16 + (q << 2));
        #pragma unroll
        for (int r = 0; r < 4; ++r) o += hout[mt4*4+r]*wo4[r];
    }
    o += __shfl_xor(o, 16); o += __shfl_xor(o, 32);
    if (q == 0 && row <= P) out[row] = o + bo[0];
}

extern "C" void kernel_launch(void* const* d_in, const int* in_sizes, int n_in,
                              void* d_out, int out_size, void* d_ws, size_t ws_size,
                              hipStream_t stream)
{
    (void)n_in; (void)out_size; (void)ws_size;
    const float* x     = (const float*)d_in[0];
    const float* W1    = (const float*)d_in[1];
    const float* b1    = (const float*)d_in[2];
    const float* g1    = (const float*)d_in[3];
    const float* be1   = (const float*)d_in[4];
    const float* l0_Wi = (const float*)d_in[5];
    const float* l0_bi = (const float*)d_in[6];
    const float* l0_bh = (const float*)d_in[8];
    const float* l0_gi = (const float*)d_in[9];
    const float* l0_bgi= (const float*)d_in[10];
    const float* l0_gh = (const float*)d_in[11];
    const float* l0_bgh= (const float*)d_in[12];
    const float* l0_gc = (const float*)d_in[13];
    const float* l0_bc = (const float*)d_in[14];
    const float* l1_Wi = (const float*)d_in[15];
    const float* l1_bi = (const float*)d_in[16];
    const float* l1_bh = (const float*)d_in[18];
    const float* l1_gi = (const float*)d_in[19];
    const float* l1_bgi= (const float*)d_in[20];
    const float* l1_gh = (const float*)d_in[21];
    const float* l1_bgh= (const float*)d_in[22];
    const float* l1_gc = (const float*)d_in[23];
    const float* l1_bc = (const float*)d_in[24];
    const float* Wo    = (const float*)d_in[25];
    const float* bo    = (const float*)d_in[26];

    int P = in_sizes[0];
    int B = P + 1;
    float* ws  = (float*)d_ws;
    float* out = (float*)d_out;

    mean_part<<<1024, 256, 0, stream>>>(x, P, ws + 16);
    mean_fin<<<1, 1024, 0, stream>>>(ws + 16, ws, P);
    precomp_kernel<<<2, 256, 0, stream>>>(
        l0_bh, l0_gh, l0_bgh, l0_bgi,
        l1_bh, l1_gh, l1_bgh, l1_bgi, ws);
    fwd_kernel<<<(B + 127)/128, 512, 0, stream>>>(
        x, W1, b1, g1, be1,
        l0_Wi, l0_bi, l0_gi, l0_gc, l0_bc,
        l1_Wi, l1_bi, l1_gi, l1_gc, l1_bc,
        Wo, bo, ws, out, P);
}